// Round 5
// baseline (109.869 us; speedup 1.0000x reference)
//
#include <hip/hip_runtime.h>

#define NH 32

using hfrag = __attribute__((ext_vector_type(8))) _Float16;
using f4v   = __attribute__((ext_vector_type(4))) float;

// ---------------------------------------------------------------------------
// Merged prep:
//   blocks [0,2048):    W3 (128k x 16384f f32) -> w3t (16384f x 128k fp16,
//                       pre-scaled by log2e so softmax uses raw v_exp_f32)
//   blocks [2048,3072): x -> xT
//   blocks [3072,3136): xms[n,d] = sum_{l masked} x[n,l,d], nmask[n] = #masked
// ---------------------------------------------------------------------------
__global__ __launch_bounds__(256) void prep_kernel(
    const float* __restrict__ W3, _Float16* __restrict__ w3t,
    const float* __restrict__ x, float* __restrict__ xT,
    const float* __restrict__ maskx, float* __restrict__ xms,
    float* __restrict__ nmask) {
  __shared__ float t[32][33];
  __shared__ float sm2[2][128];
  const int bid = blockIdx.x;
  const int tx = threadIdx.x & 31, ty = threadIdx.x >> 5;  // ty 0..7
  if (bid < 2048) {
    const int f0 = (bid & 511) * 32;
    const int k0 = (bid >> 9) * 32;
#pragma unroll
    for (int i = 0; i < 4; ++i)
      t[ty + 8 * i][tx] = W3[(size_t)(k0 + ty + 8 * i) * 16384 + f0 + tx];
    __syncthreads();
#pragma unroll
    for (int i = 0; i < 4; ++i)
      w3t[(size_t)(f0 + ty + 8 * i) * 128 + k0 + tx] =
          (_Float16)(t[tx][ty + 8 * i] * 1.44269504f);
  } else if (bid < 3072) {
    const int b2 = bid - 2048;
    const int d0 = (b2 & 3) * 32, l0 = ((b2 >> 2) & 3) * 32, n = b2 >> 4;
    const size_t base = (size_t)n * 16384;
#pragma unroll
    for (int i = 0; i < 4; ++i)
      t[ty + 8 * i][tx] = x[base + (size_t)(l0 + ty + 8 * i) * 128 + d0 + tx];
    __syncthreads();
#pragma unroll
    for (int i = 0; i < 4; ++i)
      xT[base + (size_t)(d0 + ty + 8 * i) * 128 + l0 + tx] = t[tx][ty + 8 * i];
  } else {
    const int n = bid - 3072;
    const int d = threadIdx.x & 127, seg = threadIdx.x >> 7;
    const float* xn = x + (size_t)n * 16384;
    const float* mn = maskx + n * 128;
    float acc = 0.f;
#pragma unroll 8
    for (int l = seg * 64; l < seg * 64 + 64; ++l)
      acc += (mn[l] == 0.f) ? xn[l * 128 + d] : 0.f;
    sm2[seg][d] = acc;
    __syncthreads();
    if (threadIdx.x < 128) xms[n * 128 + d] = sm2[0][d] + sm2[1][d];
    if (threadIdx.x == 0) {
      float c = 0.f;
      for (int l = 0; l < 128; ++l) c += (mn[l] == 0.f) ? 1.f : 0.f;
      nmask[n] = c;
    }
  }
}

// ---------------------------------------------------------------------------
// MLP: h2 = relu(relu(x@W1+b1)@W2+b2) * mask -> fp16. Masked l-rows are
// zeroed here so the fused kernel needs no per-element mask logic.
// grid (64 n, 4 lq), 256 thr.
// ---------------------------------------------------------------------------
__global__ __launch_bounds__(256) void mlp2_kernel(
    const float* __restrict__ x, const float* __restrict__ W1,
    const float* __restrict__ b1, const float* __restrict__ W2,
    const float* __restrict__ b2, const float* __restrict__ maskx,
    _Float16* __restrict__ h2f) {
  __shared__ float wbuf[128 * 128];   // 64 KB weights
  __shared__ float abuf[32 * 132];    // padded activations
  const int n = blockIdx.x, lq = blockIdx.y;
  const int tid = threadIdx.x;

  {
    const float4* wsrc = (const float4*)W1;
    float4* wdst = (float4*)wbuf;
#pragma unroll
    for (int i = 0; i < 16; ++i) wdst[tid + 256 * i] = wsrc[tid + 256 * i];
    const float4* xsrc = (const float4*)(x + (size_t)n * 16384 + lq * 32 * 128);
#pragma unroll
    for (int i = 0; i < 4; ++i) {
      int idx = tid + 256 * i;
      int row = idx >> 5, c4 = idx & 31;
      *(float4*)&abuf[row * 132 + c4 * 4] = xsrc[idx];
    }
  }
  __syncthreads();

  const int tl = tid >> 4, td = tid & 15;
  const int r0 = tl * 2, j0 = td * 8;
  const float m0 = maskx[n * 128 + lq * 32 + r0 + 0];
  const float m1 = maskx[n * 128 + lq * 32 + r0 + 1];
  float s[2][8];

#pragma unroll
  for (int i = 0; i < 2; ++i)
#pragma unroll
    for (int j = 0; j < 8; ++j) s[i][j] = 0.f;
#pragma unroll 4
  for (int k = 0; k < 128; ++k) {
    float a0 = abuf[(r0 + 0) * 132 + k];
    float a1 = abuf[(r0 + 1) * 132 + k];
    float4 bv0 = *(const float4*)&wbuf[k * 128 + j0];
    float4 bv1 = *(const float4*)&wbuf[k * 128 + j0 + 4];
    float b[8] = {bv0.x, bv0.y, bv0.z, bv0.w, bv1.x, bv1.y, bv1.z, bv1.w};
#pragma unroll
    for (int j = 0; j < 8; ++j) {
      s[0][j] += a0 * b[j];
      s[1][j] += a1 * b[j];
    }
  }
  __syncthreads();

#pragma unroll
  for (int i = 0; i < 2; ++i)
#pragma unroll
    for (int j = 0; j < 8; ++j)
      abuf[(r0 + i) * 132 + j0 + j] = fmaxf(s[i][j] + b1[j0 + j], 0.f);
  {
    const float4* wsrc = (const float4*)W2;
    float4* wdst = (float4*)wbuf;
#pragma unroll
    for (int i = 0; i < 16; ++i) wdst[tid + 256 * i] = wsrc[tid + 256 * i];
  }
  __syncthreads();

#pragma unroll
  for (int i = 0; i < 2; ++i)
#pragma unroll
    for (int j = 0; j < 8; ++j) s[i][j] = 0.f;
#pragma unroll 4
  for (int k = 0; k < 128; ++k) {
    float a0 = abuf[(r0 + 0) * 132 + k];
    float a1 = abuf[(r0 + 1) * 132 + k];
    float4 bv0 = *(const float4*)&wbuf[k * 128 + j0];
    float4 bv1 = *(const float4*)&wbuf[k * 128 + j0 + 4];
    float b[8] = {bv0.x, bv0.y, bv0.z, bv0.w, bv1.x, bv1.y, bv1.z, bv1.w};
#pragma unroll
    for (int j = 0; j < 8; ++j) {
      s[0][j] += a0 * b[j];
      s[1][j] += a1 * b[j];
    }
  }

  const float mm[2] = {m0, m1};
  const size_t obase = (size_t)n * 16384 + (size_t)(lq * 32) * 128;
#pragma unroll
  for (int i = 0; i < 2; ++i)
#pragma unroll
    for (int j = 0; j < 8; ++j)
      h2f[obase + (size_t)(r0 + i) * 128 + j0 + j] =
          (_Float16)(fmaxf(s[i][j] + b2[j0 + j], 0.f) * mm[i]);
}

// ---------------------------------------------------------------------------
// Fused: 512 thr, 8 waves x 16-col strips, 32 h per block, grid (64,4) =
// 1 block/CU, single round. Within-wave 2-deep pipeline: accB's MFMAs issue
// before accA's softmax (and vice versa) so the matrix pipe stays fed while
// VALU/trans run the softmax. A is re-read from swizzled LDS per group (LDS
// pipe is under the MFMA pipe cost); B double-prefetched into bA/bB. Mask
// handled algebraically (masked h2 rows are zero -> exp2(0)=1 -> subtract
// nmask from den, xms[d] from num).
// ---------------------------------------------------------------------------
__global__ __launch_bounds__(512, 2) void fused_mfma_kernel(
    const _Float16* __restrict__ h2f, const _Float16* __restrict__ w3t,
    const float* __restrict__ xT, const float* __restrict__ xms,
    const float* __restrict__ nmask, const float* __restrict__ tbias,
    float* __restrict__ out) {
  __shared__ _Float16 aLDS[128 * 128];   // 32 KB, slot-swizzled
  __shared__ float wLDS[8][NH][16];      // per-wave per-h per-col pc (16 KB)
  const int n = blockIdx.x, hg = blockIdx.y;
  const int tid = threadIdx.x;
  const int wid = tid >> 6, lane = tid & 63;
  const int r = lane & 15, kg = lane >> 4;

  // stage h2[n] (fp16, 32 KB) into LDS, swizzling 16B slots: dsl = sl^(row&7)
  const _Float16* h2n = h2f + (size_t)n * 16384;
  {
    char* lb = (char*)aLDS;
#pragma unroll
    for (int i = 0; i < 4; ++i) {
      const int og = (tid + 512 * i) * 16;  // linear global byte offset
      const int row = og >> 8;              // 256 B per row (128 fp16)
      const int sl = (og >> 4) & 15;        // 16B slot in row
      const float4 v = *(const float4*)((const char*)h2n + og);
      *(float4*)(lb + row * 256 + (sl ^ (row & 7)) * 16) = v;
    }
  }

  // this lane's x column (d = wid*16 + r), reused across all h
  f4v xv[8];
  {
    const float* xc =
        xT + (size_t)n * 16384 + (size_t)(wid * 16 + r) * 128 + kg * 4;
#pragma unroll
    for (int rt = 0; rt < 8; ++rt) xv[rt] = *(const f4v*)(xc + rt * 16);
  }
  const float xm = xms[n * 128 + wid * 16 + r];  // masked-row x sum, this col
  const float nm = nmask[n];                     // masked-row count

  __syncthreads();

  const char* lb = (const char*)aLDS;
  int dsl[4];
#pragma unroll
  for (int ks = 0; ks < 4; ++ks) dsl[ks] = ((ks * 4 + kg) ^ (r & 7)) * 16;

  // B base for this lane; per-h stride is 128*128 fp16
  const _Float16* w3g =
      w3t + ((size_t)(hg * NH) * 128 + wid * 16 + r) * 128 + kg * 8;

#define AF(KS, RT) (*(const hfrag*)(lb + ((RT)*16 + r) * 256 + dsl[KS]))

#define LOADB(B, H)                                                       \
  do {                                                                    \
    const _Float16* _p = w3g + (size_t)(H) * 16384;                       \
    _Pragma("unroll") for (int ks = 0; ks < 4; ++ks) B[ks] =              \
        *(const hfrag*)(_p + ks * 32);                                    \
  } while (0)

#define MFMA_GRP(ACC, B)                                                  \
  do {                                                                    \
    _Pragma("unroll") for (int rt = 0; rt < 8; ++rt) {                    \
      f4v _z = {0.f, 0.f, 0.f, 0.f};                                      \
      ACC[rt] = __builtin_amdgcn_mfma_f32_16x16x32_f16(AF(0, rt), B[0],   \
                                                       _z, 0, 0, 0);      \
    }                                                                     \
    _Pragma("unroll") for (int ks = 1; ks < 4; ++ks)                      \
        _Pragma("unroll") for (int rt = 0; rt < 8; ++rt) ACC[rt] =        \
            __builtin_amdgcn_mfma_f32_16x16x32_f16(AF(ks, rt), B[ks],     \
                                                   ACC[rt], 0, 0, 0);     \
  } while (0)

#define SMAX(ACC, H)                                                      \
  do {                                                                    \
    float den0 = 0.f, den1 = 0.f, num0 = 0.f, num1 = 0.f;                 \
    _Pragma("unroll") for (int rt = 0; rt < 8; rt += 2) {                 \
      _Pragma("unroll") for (int j = 0; j < 4; ++j) {                     \
        float e0 = __builtin_amdgcn_exp2f(ACC[rt][j]);                    \
        float e1 = __builtin_amdgcn_exp2f(ACC[rt + 1][j]);                 \
        den0 += e0;                                                       \
        num0 += e0 * xv[rt][j];                                           \
        den1 += e1;                                                       \
        num1 += e1 * xv[rt + 1][j];                                       \
      }                                                                   \
    }                                                                     \
    float den = den0 + den1, num = num0 + num1;                           \
    den += __shfl_xor(den, 16);                                           \
    den += __shfl_xor(den, 32);                                           \
    num += __shfl_xor(num, 16);                                           \
    num += __shfl_xor(num, 32);                                           \
    den -= nm;                                                            \
    num -= xm;                                                            \
    if (kg == 0) wLDS[wid][H][r] = num * __builtin_amdgcn_rcpf(den);      \
  } while (0)

  f4v accA[8], accB[8];
  hfrag bA[4], bB[4];

  // prologue: h=0 in flight, h=1/h=2 prefetched
  LOADB(bA, 0);
  LOADB(bB, 1);
  MFMA_GRP(accA, bA);  // h = 0
  LOADB(bA, 2);

  // steady state: branchless; the h+4 load on the last iteration reads
  // harmless in-workspace bytes (never consumed).
#pragma unroll 1
  for (int h = 0; h < NH - 2; h += 2) {
    MFMA_GRP(accB, bB);  // h+1 — fills matrix pipe during SMAX(accA)
    LOADB(bB, h + 3);
    SMAX(accA, h);
    MFMA_GRP(accA, bA);  // h+2 — fills matrix pipe during SMAX(accB)
    LOADB(bA, h + 4);
    SMAX(accB, h + 1);
  }
  // epilogue: h = NH-2, NH-1
  MFMA_GRP(accB, bB);  // NH-1
  SMAX(accA, NH - 2);
  SMAX(accB, NH - 1);

#undef AF
#undef LOADB
#undef MFMA_GRP
#undef SMAX

  __syncthreads();
  // final reduce: all 512 threads; thread (h = tid>>4, r = tid&15) sums 8
  // waves, then the 16 r-lanes fold via shfl (stays inside a 16-lane group).
  {
    const int rr = tid & 15, hh = tid >> 4;  // hh 0..31
    float s = 0.f;
#pragma unroll
    for (int w = 0; w < 8; ++w) s += wLDS[w][hh][rr];
    s += __shfl_xor(s, 1);
    s += __shfl_xor(s, 2);
    s += __shfl_xor(s, 4);
    s += __shfl_xor(s, 8);
    if (rr == 0) {
      const int h = hg * NH + hh;
      out[n * 128 + h] = fmaxf(s + tbias[h], 0.f);
    }
  }
}

// ---------------------------------------------------------------------------
extern "C" void kernel_launch(void* const* d_in, const int* in_sizes, int n_in,
                              void* d_out, int out_size, void* d_ws,
                              size_t ws_size, hipStream_t stream) {
  (void)in_sizes; (void)n_in; (void)out_size; (void)ws_size;
  const float* x     = (const float*)d_in[0];
  const float* maskx = (const float*)d_in[1];
  const float* W1    = (const float*)d_in[2];
  const float* b1    = (const float*)d_in[3];
  const float* W2    = (const float*)d_in[4];
  const float* b2    = (const float*)d_in[5];
  const float* W3    = (const float*)d_in[6];
  // d_in[7] = b3: constant along the softmax (L) axis -> cancels, unused.
  const float* tbias = (const float*)d_in[8];
  float* out = (float*)d_out;

  char* ws = (char*)d_ws;
  _Float16* w3t   = (_Float16*)ws;                          // 4 MB @ 0
  _Float16* h2f   = (_Float16*)(ws + (4u << 20));           // 2 MB @ 4M
  float*    xms   = (float*)(ws + (6u << 20));              // 32 KB @ 6M
  float*    nmask = (float*)(ws + (6u << 20) + (64u << 10));// 256 B
  float*    xT    = (float*)(ws + (8u << 20));              // 4 MB @ 8M

  prep_kernel<<<3136, 256, 0, stream>>>(W3, w3t, x, xT, maskx, xms, nmask);
  mlp2_kernel<<<dim3(64, 4), 256, 0, stream>>>(x, W1, b1, W2, b2, maskx, h2f);
  fused_mfma_kernel<<<dim3(64, 4), 512, 0, stream>>>(h2f, w3t, xT, xms,
                                                     nmask, tbias, out);
}

// Round 6
// 109.823 us; speedup vs baseline: 1.0004x; 1.0004x over previous
//
#include <hip/hip_runtime.h>

#define NH 32

using hfrag = __attribute__((ext_vector_type(8))) _Float16;
using f4v   = __attribute__((ext_vector_type(4))) float;

// ---------------------------------------------------------------------------
// Merged prep:
//   blocks [0,2048):    W3 (128k x 16384f f32) -> w3t (16384f x 128k fp16,
//                       pre-scaled by log2e so softmax uses raw v_exp_f32)
//   blocks [2048,3072): x -> xT
//   blocks [3072,3136): xms[n,d] = sum_{l masked} x[n,l,d], nmask[n] = #masked
// ---------------------------------------------------------------------------
__global__ __launch_bounds__(256) void prep_kernel(
    const float* __restrict__ W3, _Float16* __restrict__ w3t,
    const float* __restrict__ x, float* __restrict__ xT,
    const float* __restrict__ maskx, float* __restrict__ xms,
    float* __restrict__ nmask) {
  __shared__ float t[32][33];
  __shared__ float sm2[2][128];
  const int bid = blockIdx.x;
  const int tx = threadIdx.x & 31, ty = threadIdx.x >> 5;  // ty 0..7
  if (bid < 2048) {
    const int f0 = (bid & 511) * 32;
    const int k0 = (bid >> 9) * 32;
#pragma unroll
    for (int i = 0; i < 4; ++i)
      t[ty + 8 * i][tx] = W3[(size_t)(k0 + ty + 8 * i) * 16384 + f0 + tx];
    __syncthreads();
#pragma unroll
    for (int i = 0; i < 4; ++i)
      w3t[(size_t)(f0 + ty + 8 * i) * 128 + k0 + tx] =
          (_Float16)(t[tx][ty + 8 * i] * 1.44269504f);
  } else if (bid < 3072) {
    const int b2 = bid - 2048;
    const int d0 = (b2 & 3) * 32, l0 = ((b2 >> 2) & 3) * 32, n = b2 >> 4;
    const size_t base = (size_t)n * 16384;
#pragma unroll
    for (int i = 0; i < 4; ++i)
      t[ty + 8 * i][tx] = x[base + (size_t)(l0 + ty + 8 * i) * 128 + d0 + tx];
    __syncthreads();
#pragma unroll
    for (int i = 0; i < 4; ++i)
      xT[base + (size_t)(d0 + ty + 8 * i) * 128 + l0 + tx] = t[tx][ty + 8 * i];
  } else {
    const int n = bid - 3072;
    const int d = threadIdx.x & 127, seg = threadIdx.x >> 7;
    const float* xn = x + (size_t)n * 16384;
    const float* mn = maskx + n * 128;
    float acc = 0.f;
#pragma unroll 8
    for (int l = seg * 64; l < seg * 64 + 64; ++l)
      acc += (mn[l] == 0.f) ? xn[l * 128 + d] : 0.f;
    sm2[seg][d] = acc;
    __syncthreads();
    if (threadIdx.x < 128) xms[n * 128 + d] = sm2[0][d] + sm2[1][d];
    if (threadIdx.x == 0) {
      float c = 0.f;
      for (int l = 0; l < 128; ++l) c += (mn[l] == 0.f) ? 1.f : 0.f;
      nmask[n] = c;
    }
  }
}

// ---------------------------------------------------------------------------
// MLP: h2 = relu(relu(x@W1+b1)@W2+b2) * mask -> fp16. Masked l-rows are
// zeroed here so the fused kernel needs no per-element mask logic.
// grid (64 n, 4 lq), 256 thr.
// ---------------------------------------------------------------------------
__global__ __launch_bounds__(256) void mlp2_kernel(
    const float* __restrict__ x, const float* __restrict__ W1,
    const float* __restrict__ b1, const float* __restrict__ W2,
    const float* __restrict__ b2, const float* __restrict__ maskx,
    _Float16* __restrict__ h2f) {
  __shared__ float wbuf[128 * 128];   // 64 KB weights
  __shared__ float abuf[32 * 132];    // padded activations
  const int n = blockIdx.x, lq = blockIdx.y;
  const int tid = threadIdx.x;

  {
    const float4* wsrc = (const float4*)W1;
    float4* wdst = (float4*)wbuf;
#pragma unroll
    for (int i = 0; i < 16; ++i) wdst[tid + 256 * i] = wsrc[tid + 256 * i];
    const float4* xsrc = (const float4*)(x + (size_t)n * 16384 + lq * 32 * 128);
#pragma unroll
    for (int i = 0; i < 4; ++i) {
      int idx = tid + 256 * i;
      int row = idx >> 5, c4 = idx & 31;
      *(float4*)&abuf[row * 132 + c4 * 4] = xsrc[idx];
    }
  }
  __syncthreads();

  const int tl = tid >> 4, td = tid & 15;
  const int r0 = tl * 2, j0 = td * 8;
  const float m0 = maskx[n * 128 + lq * 32 + r0 + 0];
  const float m1 = maskx[n * 128 + lq * 32 + r0 + 1];
  float s[2][8];

#pragma unroll
  for (int i = 0; i < 2; ++i)
#pragma unroll
    for (int j = 0; j < 8; ++j) s[i][j] = 0.f;
#pragma unroll 4
  for (int k = 0; k < 128; ++k) {
    float a0 = abuf[(r0 + 0) * 132 + k];
    float a1 = abuf[(r0 + 1) * 132 + k];
    float4 bv0 = *(const float4*)&wbuf[k * 128 + j0];
    float4 bv1 = *(const float4*)&wbuf[k * 128 + j0 + 4];
    float b[8] = {bv0.x, bv0.y, bv0.z, bv0.w, bv1.x, bv1.y, bv1.z, bv1.w};
#pragma unroll
    for (int j = 0; j < 8; ++j) {
      s[0][j] += a0 * b[j];
      s[1][j] += a1 * b[j];
    }
  }
  __syncthreads();

#pragma unroll
  for (int i = 0; i < 2; ++i)
#pragma unroll
    for (int j = 0; j < 8; ++j)
      abuf[(r0 + i) * 132 + j0 + j] = fmaxf(s[i][j] + b1[j0 + j], 0.f);
  {
    const float4* wsrc = (const float4*)W2;
    float4* wdst = (float4*)wbuf;
#pragma unroll
    for (int i = 0; i < 16; ++i) wdst[tid + 256 * i] = wsrc[tid + 256 * i];
  }
  __syncthreads();

#pragma unroll
  for (int i = 0; i < 2; ++i)
#pragma unroll
    for (int j = 0; j < 8; ++j) s[i][j] = 0.f;
#pragma unroll 4
  for (int k = 0; k < 128; ++k) {
    float a0 = abuf[(r0 + 0) * 132 + k];
    float a1 = abuf[(r0 + 1) * 132 + k];
    float4 bv0 = *(const float4*)&wbuf[k * 128 + j0];
    float4 bv1 = *(const float4*)&wbuf[k * 128 + j0 + 4];
    float b[8] = {bv0.x, bv0.y, bv0.z, bv0.w, bv1.x, bv1.y, bv1.z, bv1.w};
#pragma unroll
    for (int j = 0; j < 8; ++j) {
      s[0][j] += a0 * b[j];
      s[1][j] += a1 * b[j];
    }
  }

  const float mm[2] = {m0, m1};
  const size_t obase = (size_t)n * 16384 + (size_t)(lq * 32) * 128;
#pragma unroll
  for (int i = 0; i < 2; ++i)
#pragma unroll
    for (int j = 0; j < 8; ++j)
      h2f[obase + (size_t)(r0 + i) * 128 + j0 + j] =
          (_Float16)(fmaxf(s[i][j] + b2[j0 + j], 0.f) * mm[i]);
}

// ---------------------------------------------------------------------------
// Fused: 512 thr, 8 waves x 16-col strips, 32 h per block, grid (64,4) =
// 1 block/CU, single round. Within-wave 2-deep pipeline: accB's MFMAs issue
// before accA's softmax (and vice versa) so the matrix pipe stays fed while
// VALU/trans run the softmax. __launch_bounds__(512, 1): empirically this
// toolchain caps VGPRs at 256/arg (r3: arg=8 -> 32, r4/r5: arg=2 -> 120/128
// with spills); arg=1 -> 256-VGPR budget for the ~180-reg live set, no spill.
// Occupancy is unchanged (8-wave block -> 2 waves/SIMD -> 1 block/CU).
// Mask handled algebraically (masked h2 rows are zero -> exp2(0)=1 ->
// subtract nmask from den, xms[d] from num).
// ---------------------------------------------------------------------------
__global__ __launch_bounds__(512, 1) void fused_mfma_kernel(
    const _Float16* __restrict__ h2f, const _Float16* __restrict__ w3t,
    const float* __restrict__ xT, const float* __restrict__ xms,
    const float* __restrict__ nmask, const float* __restrict__ tbias,
    float* __restrict__ out) {
  __shared__ _Float16 aLDS[128 * 128];   // 32 KB, slot-swizzled
  __shared__ float wLDS[8][NH][16];      // per-wave per-h per-col pc (16 KB)
  const int n = blockIdx.x, hg = blockIdx.y;
  const int tid = threadIdx.x;
  const int wid = tid >> 6, lane = tid & 63;
  const int r = lane & 15, kg = lane >> 4;

  // stage h2[n] (fp16, 32 KB) into LDS, swizzling 16B slots: dsl = sl^(row&7)
  const _Float16* h2n = h2f + (size_t)n * 16384;
  {
    char* lb = (char*)aLDS;
#pragma unroll
    for (int i = 0; i < 4; ++i) {
      const int og = (tid + 512 * i) * 16;  // linear global byte offset
      const int row = og >> 8;              // 256 B per row (128 fp16)
      const int sl = (og >> 4) & 15;        // 16B slot in row
      const float4 v = *(const float4*)((const char*)h2n + og);
      *(float4*)(lb + row * 256 + (sl ^ (row & 7)) * 16) = v;
    }
  }

  // this lane's x column (d = wid*16 + r), reused across all h
  f4v xv[8];
  {
    const float* xc =
        xT + (size_t)n * 16384 + (size_t)(wid * 16 + r) * 128 + kg * 4;
#pragma unroll
    for (int rt = 0; rt < 8; ++rt) xv[rt] = *(const f4v*)(xc + rt * 16);
  }
  const float xm = xms[n * 128 + wid * 16 + r];  // masked-row x sum, this col
  const float nm = nmask[n];                     // masked-row count

  __syncthreads();

  const char* lb = (const char*)aLDS;
  int dsl[4];
#pragma unroll
  for (int ks = 0; ks < 4; ++ks) dsl[ks] = ((ks * 4 + kg) ^ (r & 7)) * 16;

  // B base for this lane; per-h stride is 128*128 fp16
  const _Float16* w3g =
      w3t + ((size_t)(hg * NH) * 128 + wid * 16 + r) * 128 + kg * 8;

#define AF(KS, RT) (*(const hfrag*)(lb + ((RT)*16 + r) * 256 + dsl[KS]))

#define LOADB(B, H)                                                       \
  do {                                                                    \
    const _Float16* _p = w3g + (size_t)(H) * 16384;                       \
    _Pragma("unroll") for (int ks = 0; ks < 4; ++ks) B[ks] =              \
        *(const hfrag*)(_p + ks * 32);                                    \
  } while (0)

#define MFMA_GRP(ACC, B)                                                  \
  do {                                                                    \
    _Pragma("unroll") for (int rt = 0; rt < 8; ++rt) {                    \
      f4v _z = {0.f, 0.f, 0.f, 0.f};                                      \
      ACC[rt] = __builtin_amdgcn_mfma_f32_16x16x32_f16(AF(0, rt), B[0],   \
                                                       _z, 0, 0, 0);      \
    }                                                                     \
    _Pragma("unroll") for (int ks = 1; ks < 4; ++ks)                      \
        _Pragma("unroll") for (int rt = 0; rt < 8; ++rt) ACC[rt] =        \
            __builtin_amdgcn_mfma_f32_16x16x32_f16(AF(ks, rt), B[ks],     \
                                                   ACC[rt], 0, 0, 0);     \
  } while (0)

#define SMAX(ACC, H)                                                      \
  do {                                                                    \
    float den0 = 0.f, den1 = 0.f, num0 = 0.f, num1 = 0.f;                 \
    _Pragma("unroll") for (int rt = 0; rt < 8; rt += 2) {                 \
      _Pragma("unroll") for (int j = 0; j < 4; ++j) {                     \
        float e0 = __builtin_amdgcn_exp2f(ACC[rt][j]);                    \
        float e1 = __builtin_amdgcn_exp2f(ACC[rt + 1][j]);                 \
        den0 += e0;                                                       \
        num0 += e0 * xv[rt][j];                                           \
        den1 += e1;                                                       \
        num1 += e1 * xv[rt + 1][j];                                       \
      }                                                                   \
    }                                                                     \
    float den = den0 + den1, num = num0 + num1;                           \
    den += __shfl_xor(den, 16);                                           \
    den += __shfl_xor(den, 32);                                           \
    num += __shfl_xor(num, 16);                                           \
    num += __shfl_xor(num, 32);                                           \
    den -= nm;                                                            \
    num -= xm;                                                            \
    if (kg == 0) wLDS[wid][H][r] = num * __builtin_amdgcn_rcpf(den);      \
  } while (0)

  f4v accA[8], accB[8];
  hfrag bA[4], bB[4];

  // prologue: h=0 in flight, h=1/h=2 prefetched
  LOADB(bA, 0);
  LOADB(bB, 1);
  MFMA_GRP(accA, bA);  // h = 0
  LOADB(bA, 2);

  // steady state: branchless; the h+4 load on the last iteration reads
  // harmless in-workspace bytes (never consumed).
#pragma unroll 1
  for (int h = 0; h < NH - 2; h += 2) {
    MFMA_GRP(accB, bB);  // h+1 — fills matrix pipe during SMAX(accA)
    LOADB(bB, h + 3);
    SMAX(accA, h);
    MFMA_GRP(accA, bA);  // h+2 — fills matrix pipe during SMAX(accB)
    LOADB(bA, h + 4);
    SMAX(accB, h + 1);
  }
  // epilogue: h = NH-2, NH-1
  MFMA_GRP(accB, bB);  // NH-1
  SMAX(accA, NH - 2);
  SMAX(accB, NH - 1);

#undef AF
#undef LOADB
#undef MFMA_GRP
#undef SMAX

  __syncthreads();
  // final reduce: all 512 threads; thread (h = tid>>4, r = tid&15) sums 8
  // waves, then the 16 r-lanes fold via shfl (stays inside a 16-lane group).
  {
    const int rr = tid & 15, hh = tid >> 4;  // hh 0..31
    float s = 0.f;
#pragma unroll
    for (int w = 0; w < 8; ++w) s += wLDS[w][hh][rr];
    s += __shfl_xor(s, 1);
    s += __shfl_xor(s, 2);
    s += __shfl_xor(s, 4);
    s += __shfl_xor(s, 8);
    if (rr == 0) {
      const int h = hg * NH + hh;
      out[n * 128 + h] = fmaxf(s + tbias[h], 0.f);
    }
  }
}

// ---------------------------------------------------------------------------
extern "C" void kernel_launch(void* const* d_in, const int* in_sizes, int n_in,
                              void* d_out, int out_size, void* d_ws,
                              size_t ws_size, hipStream_t stream) {
  (void)in_sizes; (void)n_in; (void)out_size; (void)ws_size;
  const float* x     = (const float*)d_in[0];
  const float* maskx = (const float*)d_in[1];
  const float* W1    = (const float*)d_in[2];
  const float* b1    = (const float*)d_in[3];
  const float* W2    = (const float*)d_in[4];
  const float* b2    = (const float*)d_in[5];
  const float* W3    = (const float*)d_in[6];
  // d_in[7] = b3: constant along the softmax (L) axis -> cancels, unused.
  const float* tbias = (const float*)d_in[8];
  float* out = (float*)d_out;

  char* ws = (char*)d_ws;
  _Float16* w3t   = (_Float16*)ws;                          // 4 MB @ 0
  _Float16* h2f   = (_Float16*)(ws + (4u << 20));           // 2 MB @ 4M
  float*    xms   = (float*)(ws + (6u << 20));              // 32 KB @ 6M
  float*    nmask = (float*)(ws + (6u << 20) + (64u << 10));// 256 B
  float*    xT    = (float*)(ws + (8u << 20));              // 4 MB @ 8M

  prep_kernel<<<3136, 256, 0, stream>>>(W3, w3t, x, xT, maskx, xms, nmask);
  mlp2_kernel<<<dim3(64, 4), 256, 0, stream>>>(x, W1, b1, W2, b2, maskx, h2f);
  fused_mfma_kernel<<<dim3(64, 4), 512, 0, stream>>>(h2f, w3t, xT, xms,
                                                     nmask, tbias, out);
}

// Round 7
// 99.063 us; speedup vs baseline: 1.1091x; 1.1086x over previous
//
#include <hip/hip_runtime.h>

#define NH 32

using hfrag = __attribute__((ext_vector_type(8))) _Float16;
using f4v   = __attribute__((ext_vector_type(4))) float;

// ---------------------------------------------------------------------------
// Merged prep:
//   blocks [0,2048):    W3 (128k x 16384f f32) -> w3t (16384f x 128k fp16,
//                       pre-scaled by log2e so softmax uses raw v_exp_f32)
//   blocks [2048,3072): x -> xT
//   blocks [3072,3136): xms[n,d] = sum_{l masked} x[n,l,d], nmask[n] = #masked
// ---------------------------------------------------------------------------
__global__ __launch_bounds__(256) void prep_kernel(
    const float* __restrict__ W3, _Float16* __restrict__ w3t,
    const float* __restrict__ x, float* __restrict__ xT,
    const float* __restrict__ maskx, float* __restrict__ xms,
    float* __restrict__ nmask) {
  __shared__ float t[32][33];
  __shared__ float sm2[2][128];
  const int bid = blockIdx.x;
  const int tx = threadIdx.x & 31, ty = threadIdx.x >> 5;  // ty 0..7
  if (bid < 2048) {
    const int f0 = (bid & 511) * 32;
    const int k0 = (bid >> 9) * 32;
#pragma unroll
    for (int i = 0; i < 4; ++i)
      t[ty + 8 * i][tx] = W3[(size_t)(k0 + ty + 8 * i) * 16384 + f0 + tx];
    __syncthreads();
#pragma unroll
    for (int i = 0; i < 4; ++i)
      w3t[(size_t)(f0 + ty + 8 * i) * 128 + k0 + tx] =
          (_Float16)(t[tx][ty + 8 * i] * 1.44269504f);
  } else if (bid < 3072) {
    const int b2 = bid - 2048;
    const int d0 = (b2 & 3) * 32, l0 = ((b2 >> 2) & 3) * 32, n = b2 >> 4;
    const size_t base = (size_t)n * 16384;
#pragma unroll
    for (int i = 0; i < 4; ++i)
      t[ty + 8 * i][tx] = x[base + (size_t)(l0 + ty + 8 * i) * 128 + d0 + tx];
    __syncthreads();
#pragma unroll
    for (int i = 0; i < 4; ++i)
      xT[base + (size_t)(d0 + ty + 8 * i) * 128 + l0 + tx] = t[tx][ty + 8 * i];
  } else {
    const int n = bid - 3072;
    const int d = threadIdx.x & 127, seg = threadIdx.x >> 7;
    const float* xn = x + (size_t)n * 16384;
    const float* mn = maskx + n * 128;
    float acc = 0.f;
#pragma unroll 8
    for (int l = seg * 64; l < seg * 64 + 64; ++l)
      acc += (mn[l] == 0.f) ? xn[l * 128 + d] : 0.f;
    sm2[seg][d] = acc;
    __syncthreads();
    if (threadIdx.x < 128) xms[n * 128 + d] = sm2[0][d] + sm2[1][d];
    if (threadIdx.x == 0) {
      float c = 0.f;
      for (int l = 0; l < 128; ++l) c += (mn[l] == 0.f) ? 1.f : 0.f;
      nmask[n] = c;
    }
  }
}

// ---------------------------------------------------------------------------
// MLP: h2 = relu(relu(x@W1+b1)@W2+b2) * mask -> fp16. Masked l-rows are
// zeroed here so the fused kernel needs no per-element mask logic.
// grid (64 n, 4 lq), 256 thr.
// ---------------------------------------------------------------------------
__global__ __launch_bounds__(256) void mlp2_kernel(
    const float* __restrict__ x, const float* __restrict__ W1,
    const float* __restrict__ b1, const float* __restrict__ W2,
    const float* __restrict__ b2, const float* __restrict__ maskx,
    _Float16* __restrict__ h2f) {
  __shared__ float wbuf[128 * 128];   // 64 KB weights
  __shared__ float abuf[32 * 132];    // padded activations
  const int n = blockIdx.x, lq = blockIdx.y;
  const int tid = threadIdx.x;

  {
    const float4* wsrc = (const float4*)W1;
    float4* wdst = (float4*)wbuf;
#pragma unroll
    for (int i = 0; i < 16; ++i) wdst[tid + 256 * i] = wsrc[tid + 256 * i];
    const float4* xsrc = (const float4*)(x + (size_t)n * 16384 + lq * 32 * 128);
#pragma unroll
    for (int i = 0; i < 4; ++i) {
      int idx = tid + 256 * i;
      int row = idx >> 5, c4 = idx & 31;
      *(float4*)&abuf[row * 132 + c4 * 4] = xsrc[idx];
    }
  }
  __syncthreads();

  const int tl = tid >> 4, td = tid & 15;
  const int r0 = tl * 2, j0 = td * 8;
  const float m0 = maskx[n * 128 + lq * 32 + r0 + 0];
  const float m1 = maskx[n * 128 + lq * 32 + r0 + 1];
  float s[2][8];

#pragma unroll
  for (int i = 0; i < 2; ++i)
#pragma unroll
    for (int j = 0; j < 8; ++j) s[i][j] = 0.f;
#pragma unroll 4
  for (int k = 0; k < 128; ++k) {
    float a0 = abuf[(r0 + 0) * 132 + k];
    float a1 = abuf[(r0 + 1) * 132 + k];
    float4 bv0 = *(const float4*)&wbuf[k * 128 + j0];
    float4 bv1 = *(const float4*)&wbuf[k * 128 + j0 + 4];
    float b[8] = {bv0.x, bv0.y, bv0.z, bv0.w, bv1.x, bv1.y, bv1.z, bv1.w};
#pragma unroll
    for (int j = 0; j < 8; ++j) {
      s[0][j] += a0 * b[j];
      s[1][j] += a1 * b[j];
    }
  }
  __syncthreads();

#pragma unroll
  for (int i = 0; i < 2; ++i)
#pragma unroll
    for (int j = 0; j < 8; ++j)
      abuf[(r0 + i) * 132 + j0 + j] = fmaxf(s[i][j] + b1[j0 + j], 0.f);
  {
    const float4* wsrc = (const float4*)W2;
    float4* wdst = (float4*)wbuf;
#pragma unroll
    for (int i = 0; i < 16; ++i) wdst[tid + 256 * i] = wsrc[tid + 256 * i];
  }
  __syncthreads();

#pragma unroll
  for (int i = 0; i < 2; ++i)
#pragma unroll
    for (int j = 0; j < 8; ++j) s[i][j] = 0.f;
#pragma unroll 4
  for (int k = 0; k < 128; ++k) {
    float a0 = abuf[(r0 + 0) * 132 + k];
    float a1 = abuf[(r0 + 1) * 132 + k];
    float4 bv0 = *(const float4*)&wbuf[k * 128 + j0];
    float4 bv1 = *(const float4*)&wbuf[k * 128 + j0 + 4];
    float b[8] = {bv0.x, bv0.y, bv0.z, bv0.w, bv1.x, bv1.y, bv1.z, bv1.w};
#pragma unroll
    for (int j = 0; j < 8; ++j) {
      s[0][j] += a0 * b[j];
      s[1][j] += a1 * b[j];
    }
  }

  const float mm[2] = {m0, m1};
  const size_t obase = (size_t)n * 16384 + (size_t)(lq * 32) * 128;
#pragma unroll
  for (int i = 0; i < 2; ++i)
#pragma unroll
    for (int j = 0; j < 8; ++j)
      h2f[obase + (size_t)(r0 + i) * 128 + j0 + j] =
          (_Float16)(fmaxf(s[i][j] + b2[j0 + j], 0.f) * mm[i]);
}

// ---------------------------------------------------------------------------
// Fused: 512 thr, 8 waves = 2 l-halves x 4 col-groups; 32 h per block,
// grid (64,4) = 1 block/CU, single round. Each wave: l in [H*64, +64),
// cols [wset*32, +32) (2 ct). Each A-frag LDS read feeds 2 MFMAs -> per-CU
// LDS traffic halved vs 16-col waves (the r4 bottleneck). Live set ~115
// VGPR -> fits the toolchain's 128-VGPR cap for 512-thr blocks, no spill.
// B single-buffered: LOADB(h) issues before SMAX(h-1), latency hidden.
// den/num per (h,ct,r) dumped to LDS; one final pass combines l-halves,
// applies the algebraic mask correction (masked h2 rows are zero ->
// exp2(0)=1 -> den-=nmask, num-=xms[d]), divides and reduces over d.
// ---------------------------------------------------------------------------
__global__ __launch_bounds__(512) void fused_mfma_kernel(
    const _Float16* __restrict__ h2f, const _Float16* __restrict__ w3t,
    const float* __restrict__ xT, const float* __restrict__ xms,
    const float* __restrict__ nmask, const float* __restrict__ tbias,
    float* __restrict__ out) {
  __shared__ _Float16 aLDS[128 * 128];     // 32 KB, slot-swizzled
  __shared__ float wp[8][NH][2][16][2];    // [wave][h][ct][r][den,num] 64 KB
  const int n = blockIdx.x, hg = blockIdx.y;
  const int tid = threadIdx.x;
  const int wid = tid >> 6, lane = tid & 63;
  const int r = lane & 15, kg = lane >> 4;
  const int wset = wid & 3;       // column group: cols [wset*32, +32)
  const int H = wid >> 2;         // l-half: rows [H*64, +64)

  // stage h2[n] (fp16, 32 KB) into LDS, swizzling 16B slots: dsl = sl^(row&7)
  const _Float16* h2n = h2f + (size_t)n * 16384;
  {
    char* lb = (char*)aLDS;
#pragma unroll
    for (int i = 0; i < 4; ++i) {
      const int og = (tid + 512 * i) * 16;  // linear global byte offset
      const int row = og >> 8;              // 256 B per row (128 fp16)
      const int sl = (og >> 4) & 15;        // 16B slot in row
      const float4 v = *(const float4*)((const char*)h2n + og);
      *(float4*)(lb + row * 256 + (sl ^ (row & 7)) * 16) = v;
    }
  }

  // this lane's x values: x[l, d] for l = H*64 + rt*16 + kg*4 + j,
  // d = wset*32 + ct*16 + r; reused across all h
  f4v xv[2][4];
#pragma unroll
  for (int ct = 0; ct < 2; ++ct) {
    const float* xc = xT + (size_t)n * 16384 +
                      (size_t)(wset * 32 + ct * 16 + r) * 128 + H * 64 + kg * 4;
#pragma unroll
    for (int rt = 0; rt < 4; ++rt) xv[ct][rt] = *(const f4v*)(xc + rt * 16);
  }

  __syncthreads();

  const char* lb = (const char*)aLDS;
  int dsl[4];
#pragma unroll
  for (int ks = 0; ks < 4; ++ks) dsl[ks] = ((ks * 4 + kg) ^ (r & 7)) * 16;
  const int rowBase = (H * 64 + r) * 256;

  // B base for this lane; per-h stride is 128*128 fp16
  const _Float16* w3g =
      w3t + ((size_t)(hg * NH) * 128 + wset * 32 + r) * 128 + kg * 8;

  hfrag b[4][2];
  f4v acc[4][2];

#define LOADB(h)                                                          \
  do {                                                                    \
    const _Float16* _p = w3g + (size_t)(h) * 16384;                       \
    _Pragma("unroll") for (int ks = 0; ks < 4; ++ks) {                    \
      b[ks][0] = *(const hfrag*)(_p + ks * 32);                           \
      b[ks][1] = *(const hfrag*)(_p + 16 * 128 + ks * 32);                \
    }                                                                     \
  } while (0)

#define MFMA_GRP()                                                        \
  do {                                                                    \
    _Pragma("unroll") for (int rt = 0; rt < 4; ++rt) {                    \
      f4v _z = {0.f, 0.f, 0.f, 0.f};                                      \
      hfrag _a = *(const hfrag*)(lb + rowBase + rt * 16 * 256 + dsl[0]);  \
      acc[rt][0] =                                                        \
          __builtin_amdgcn_mfma_f32_16x16x32_f16(_a, b[0][0], _z, 0, 0, 0);\
      acc[rt][1] =                                                        \
          __builtin_amdgcn_mfma_f32_16x16x32_f16(_a, b[0][1], _z, 0, 0, 0);\
    }                                                                     \
    _Pragma("unroll") for (int ks = 1; ks < 4; ++ks)                      \
        _Pragma("unroll") for (int rt = 0; rt < 4; ++rt) {                \
      hfrag _a = *(const hfrag*)(lb + rowBase + rt * 16 * 256 + dsl[ks]); \
      acc[rt][0] = __builtin_amdgcn_mfma_f32_16x16x32_f16(_a, b[ks][0],   \
                                                          acc[rt][0], 0, 0, 0);\
      acc[rt][1] = __builtin_amdgcn_mfma_f32_16x16x32_f16(_a, b[ks][1],   \
                                                          acc[rt][1], 0, 0, 0);\
    }                                                                     \
  } while (0)

#define SMAX(h)                                                           \
  do {                                                                    \
    _Pragma("unroll") for (int ct = 0; ct < 2; ++ct) {                    \
      float den0 = 0.f, den1 = 0.f, num0 = 0.f, num1 = 0.f;               \
      _Pragma("unroll") for (int rt = 0; rt < 4; rt += 2) {               \
        _Pragma("unroll") for (int j = 0; j < 4; ++j) {                   \
          float e0 = __builtin_amdgcn_exp2f(acc[rt][ct][j]);              \
          float e1 = __builtin_amdgcn_exp2f(acc[rt + 1][ct][j]);          \
          den0 += e0;                                                     \
          num0 += e0 * xv[ct][rt][j];                                     \
          den1 += e1;                                                     \
          num1 += e1 * xv[ct][rt + 1][j];                                 \
        }                                                                 \
      }                                                                   \
      float den = den0 + den1, num = num0 + num1;                         \
      den += __shfl_xor(den, 16);                                         \
      den += __shfl_xor(den, 32);                                         \
      num += __shfl_xor(num, 16);                                         \
      num += __shfl_xor(num, 32);                                         \
      if (kg == 0) {                                                      \
        wp[wid][h][ct][r][0] = den;                                       \
        wp[wid][h][ct][r][1] = num;                                       \
      }                                                                   \
    }                                                                     \
  } while (0)

  // prologue
  LOADB(0);
  MFMA_GRP();  // h = 0
  // steady state: LOADB(h) hides under SMAX(h-1); b regs free after the
  // previous MFMA_GRP, acc freed by SMAX before MFMA_GRP rewrites it.
#pragma unroll 1
  for (int h = 1; h < NH; ++h) {
    LOADB(h);
    SMAX(h - 1);
    MFMA_GRP();
  }
  SMAX(NH - 1);

#undef LOADB
#undef MFMA_GRP
#undef SMAX

  __syncthreads();

  // final combine: thread (h = tid>>4, r = tid&15); for each of 8 col-slots
  // combine the two l-halves, apply mask correction, divide, accumulate;
  // then fold the 16 r-lanes.
  {
    const int rr = tid & 15, hh = tid >> 4;  // hh 0..31
    const float nm = nmask[n];
    const float* xmn = xms + n * 128;
    float s = 0.f;
#pragma unroll
    for (int ws = 0; ws < 4; ++ws)
#pragma unroll
      for (int ct = 0; ct < 2; ++ct) {
        const int d = ws * 32 + ct * 16 + rr;
        float den = wp[ws][hh][ct][rr][0] + wp[ws + 4][hh][ct][rr][0] - nm;
        float num = wp[ws][hh][ct][rr][1] + wp[ws + 4][hh][ct][rr][1] - xmn[d];
        s += num * __builtin_amdgcn_rcpf(den);
      }
    s += __shfl_xor(s, 1);
    s += __shfl_xor(s, 2);
    s += __shfl_xor(s, 4);
    s += __shfl_xor(s, 8);
    if (rr == 0) {
      const int h = hg * NH + hh;
      out[n * 128 + h] = fmaxf(s + tbias[h], 0.f);
    }
  }
}

// ---------------------------------------------------------------------------
extern "C" void kernel_launch(void* const* d_in, const int* in_sizes, int n_in,
                              void* d_out, int out_size, void* d_ws,
                              size_t ws_size, hipStream_t stream) {
  (void)in_sizes; (void)n_in; (void)out_size; (void)ws_size;
  const float* x     = (const float*)d_in[0];
  const float* maskx = (const float*)d_in[1];
  const float* W1    = (const float*)d_in[2];
  const float* b1    = (const float*)d_in[3];
  const float* W2    = (const float*)d_in[4];
  const float* b2    = (const float*)d_in[5];
  const float* W3    = (const float*)d_in[6];
  // d_in[7] = b3: constant along the softmax (L) axis -> cancels, unused.
  const float* tbias = (const float*)d_in[8];
  float* out = (float*)d_out;

  char* ws = (char*)d_ws;
  _Float16* w3t   = (_Float16*)ws;                          // 4 MB @ 0
  _Float16* h2f   = (_Float16*)(ws + (4u << 20));           // 2 MB @ 4M
  float*    xms   = (float*)(ws + (6u << 20));              // 32 KB @ 6M
  float*    nmask = (float*)(ws + (6u << 20) + (64u << 10));// 256 B
  float*    xT    = (float*)(ws + (8u << 20));              // 4 MB @ 8M

  prep_kernel<<<3136, 256, 0, stream>>>(W3, w3t, x, xT, maskx, xms, nmask);
  mlp2_kernel<<<dim3(64, 4), 256, 0, stream>>>(x, W1, b1, W2, b2, maskx, h2f);
  fused_mfma_kernel<<<dim3(64, 4), 512, 0, stream>>>(h2f, w3t, xT, xms,
                                                     nmask, tbias, out);
}